// Round 1
// baseline (262.633 us; speedup 1.0000x reference)
//
#include <hip/hip_runtime.h>

typedef short s16x8 __attribute__((ext_vector_type(8)));
typedef float f32x4 __attribute__((ext_vector_type(4)));
typedef unsigned short us;

__device__ inline us f2bf(float f){
    union{float f;unsigned u;} v{f};
    unsigned r = v.u + 0x7fff + ((v.u>>16)&1);
    return (us)(r>>16);
}

__device__ __forceinline__ void glds16(const us* g, us* l){
    __builtin_amdgcn_global_load_lds(
        (const __attribute__((address_space(1))) unsigned int*)(g),
        (__attribute__((address_space(3))) unsigned int*)(l), 16, 0, 0);
}

// ---------------- fused cast: x, wqkv_w, wp_w -> bf16, one launch ----------------
__global__ void cast_all(const float* __restrict__ x, const float* __restrict__ wqkv_w,
                         const float* __restrict__ wp_w, us* __restrict__ xbf,
                         us* __restrict__ wqkvbf, us* __restrict__ wpbf){
    int i = blockIdx.x*blockDim.x + threadIdx.x;   // 4456448 float4s
    const float* s; us* d; int j;
    if(i < 4194304){ s = x; d = xbf; j = i; }
    else if(i < 4390912){ s = wqkv_w; d = wqkvbf; j = i - 4194304; }
    else { s = wp_w; d = wpbf; j = i - 4390912; }
    float4 f = ((const float4*)s)[j];
    ushort4 o;
    o.x = f2bf(f.x); o.y = f2bf(f.y); o.z = f2bf(f.z); o.w = f2bf(f.w);
    ((ushort4*)d)[j] = o;
}

// ==== qkv = xbf @ wqkv^T + b  (M=32768,N=1536,K=512) ====
// 256x256 tile, 8 waves (2M x 4N), BK=64, double-buffered LDS (128 KiB),
// deep pipeline: stage tile t+1 at phase 0 of tile t; only ONE vmcnt wait per
// tile at the boundary (raw s_barrier everywhere -> loads stay in flight
// across phase barriers, unlike __syncthreads which drains vmcnt to 0).
// 4 MFMA phases/tile (16 MFMA each) wrapped in setprio for wave role-split.
__launch_bounds__(512,2)
__global__ void gemm_qkv(const us* __restrict__ A, const us* __restrict__ B,
                         const float* __restrict__ bias, us* __restrict__ C){
    __shared__ __attribute__((aligned(16))) us sA[2][16384];
    __shared__ __attribute__((aligned(16))) us sB[2][16384];
    int t = threadIdx.x;
    int id = blockIdx.x;                 // 768 = 8 XCD * 96
    int xcd = id & 7, s = id >> 3;       // bijective XCD swizzle (768 % 8 == 0)
    int nt = s % 6, mt = xcd*16 + s/6;   // Mt=128, Nt=6
    int lane = t&63, wave = t>>6, quad = lane>>4, l15 = lane&15;
    int wm = wave>>2, wn = wave&3;       // wave tile: 128 rows x 64 cols
    int l8 = lane>>3;
    int sw = ((lane&7) ^ l8)*8;          // pre-swizzled global source (rule #21)

    // round r covers LDS rows r*64 + wave*8 + l8  (global row = mt*256 + LDS row)
    const us* Ag = A + (size_t)(mt*256 + wave*8 + l8)*512 + sw;
    const us* Bg = B + (size_t)(nt*256 + wave*8 + l8)*512 + sw;
    us* sA0 = &sA[0][0];
    us* sB0 = &sB[0][0];
    int wofs = wave*512;                 // wave-uniform LDS dest base (glds16 req.)

    f32x4 acc[8][4];
    #pragma unroll
    for(int m=0;m<8;m++)
        #pragma unroll
        for(int n=0;n<4;n++) acc[m][n] = (f32x4){0.f,0.f,0.f,0.f};

    // prologue: stage K-tile 0 into buf0
    #pragma unroll
    for(int r=0;r<4;r++) glds16(Ag + r*32768, sA0 + wofs + r*4096);
    #pragma unroll
    for(int r=0;r<4;r++) glds16(Bg + r*32768, sB0 + wofs + r*4096);
    asm volatile("s_waitcnt vmcnt(0)" ::: "memory");
    __builtin_amdgcn_s_barrier();

    for(int kt=0; kt<8; ++kt){
        int cur = kt & 1;
        const us* sAc = sA0 + cur*16384;
        const us* sBc = sB0 + cur*16384;
        // phase 0 staging: issue ALL of tile kt+1 now -> max issue-to-wait gap
        if(kt < 7){
            int kn = (kt+1)*64;
            int nx = (cur^1)*16384 + wofs;
            #pragma unroll
            for(int r=0;r<4;r++) glds16(Ag + r*32768 + kn, sA0 + nx + r*4096);
            #pragma unroll
            for(int r=0;r<4;r++) glds16(Bg + r*32768 + kn, sB0 + nx + r*4096);
        }
        // phase 0 ds-reads: all 8 B frags (held whole tile) + first A pair
        s16x8 bfr[4][2];
        #pragma unroll
        for(int n=0;n<4;n++){
            int rw = wn*64 + n*16 + l15;
            #pragma unroll
            for(int ks=0;ks<2;ks++){
                int kc = ks*4 + quad;
                bfr[n][ks] = *(const s16x8*)&sBc[rw*64 + ((kc ^ (rw&7))<<3)];
            }
        }
        #pragma unroll
        for(int p=0;p<4;p++){
            s16x8 af[2][2];
            #pragma unroll
            for(int i=0;i<2;i++){
                int rw = wm*128 + (2*p+i)*16 + l15;
                #pragma unroll
                for(int ks=0;ks<2;ks++){
                    int kc = ks*4 + quad;
                    af[i][ks] = *(const s16x8*)&sAc[rw*64 + ((kc ^ (rw&7))<<3)];
                }
            }
            __builtin_amdgcn_s_barrier();
            __builtin_amdgcn_s_setprio(1);
            #pragma unroll
            for(int ks=0;ks<2;ks++)
                #pragma unroll
                for(int i=0;i<2;i++)
                    #pragma unroll
                    for(int n=0;n<4;n++)
                        acc[2*p+i][n] = __builtin_amdgcn_mfma_f32_16x16x32_bf16(
                                            af[i][ks], bfr[n][ks], acc[2*p+i][n], 0,0,0);
            __builtin_amdgcn_s_setprio(0);
            __builtin_amdgcn_s_barrier();
        }
        if(kt < 7){
            // only vmem wait in the loop; loads were issued ~1 full tile ago
            asm volatile("s_waitcnt vmcnt(0)" ::: "memory");
            __builtin_amdgcn_s_barrier();
        }
    }

    int row0 = mt*256 + wm*128, col0 = nt*256 + wn*64;
    #pragma unroll
    for(int n=0;n<4;n++){
        int col = col0 + n*16 + l15;
        float bv = bias[col];
        #pragma unroll
        for(int m=0;m<8;m++){
            int rb = row0 + m*16 + quad*4;
            #pragma unroll
            for(int r=0;r<4;r++)
                C[(size_t)(rb+r)*1536 + col] = f2bf(acc[m][n][r] + bv);
        }
    }
}

// ---- scores: Spart[kb][head][d][e] = partial over 512 tokens (kb<8, 8 chunks) ----
__launch_bounds__(256,4)
__global__ void attn_scores_mfma(const us* __restrict__ qkv, float* __restrict__ Sp){
    __shared__ __attribute__((aligned(16))) us sQt[64*72];
    __shared__ __attribute__((aligned(16))) us sKt[64*72];
    int t = threadIdx.x;
    int kb = blockIdx.x, head = blockIdx.y;   // kb < 8
    int lane = t & 63, w = t >> 6;
    int quad = lane >> 4, l15 = lane & 15;
    int p = t & 31;
    int d0 = (t >> 5) * 8;

    f32x4 acc[4];
    #pragma unroll
    for(int j=0;j<4;j++) acc[j] = (f32x4){0.f,0.f,0.f,0.f};

    for(int chunk=0; chunk<8; chunk++){
        int r0 = head*512 + kb*64 + chunk*8;
        const us* g = qkv + (size_t)(r0 + (p>>2))*1536 + (2*(p&3))*64 + d0;
        union{uint4 v; us h[8];} q0, q1, k0, k1;
        q0.v = *(const uint4*)g;         q1.v = *(const uint4*)(g + 64);
        k0.v = *(const uint4*)(g + 512); k1.v = *(const uint4*)(g + 576);
        #pragma unroll
        for(int j=0;j<8;j++){
            *(unsigned*)&sQt[(d0+j)*72 + 2*p] = (unsigned)q0.h[j] | ((unsigned)q1.h[j]<<16);
            *(unsigned*)&sKt[(d0+j)*72 + 2*p] = (unsigned)k0.h[j] | ((unsigned)k1.h[j]<<16);
        }
        __syncthreads();
        int d = w*16 + l15;
        #pragma unroll
        for(int ks=0; ks<2; ks++){
            int tb = ks*4 + quad;
            s16x8 af = *(const s16x8*)&sQt[d*72 + tb*8];
            #pragma unroll
            for(int jt=0; jt<4; jt++){
                int e = jt*16 + l15;
                s16x8 bfv = *(const s16x8*)&sKt[e*72 + tb*8];
                acc[jt] = __builtin_amdgcn_mfma_f32_16x16x32_bf16(af, bfv, acc[jt], 0,0,0);
            }
        }
        __syncthreads();
    }

    float* S = Sp + (size_t)(kb*64 + head)*4096;
    #pragma unroll
    for(int jt=0; jt<4; jt++){
        int e = jt*16 + l15;
        #pragma unroll
        for(int r=0; r<4; r++){
            int d = w*16 + quad*4 + r;
            S[d*64 + e] = acc[jt][r];
        }
    }
}

// ---- sum 8 partials, softmax over e (scale 1/8); 256 blocks (4 d-strips/head) ----
__global__ void softmax64(const float* __restrict__ Sp, us* __restrict__ W){
    int head = blockIdx.x>>2, part = blockIdx.x&3;
    int t = threadIdx.x;           // 256
    int d = part*16 + (t>>4), e0 = (t&15)*4;
    float4 v = {0.f,0.f,0.f,0.f};
    for(int kb=0; kb<8; kb++){
        float4 f = *(const float4*)&Sp[(size_t)(kb*64 + head)*4096 + d*64 + e0];
        v.x+=f.x; v.y+=f.y; v.z+=f.z; v.w+=f.w;
    }
    v.x*=0.125f; v.y*=0.125f; v.z*=0.125f; v.w*=0.125f;
    float m = fmaxf(fmaxf(v.x,v.y), fmaxf(v.z,v.w));
    m = fmaxf(m, __shfl_xor(m, 1));
    m = fmaxf(m, __shfl_xor(m, 2));
    m = fmaxf(m, __shfl_xor(m, 4));
    m = fmaxf(m, __shfl_xor(m, 8));
    v.x=__expf(v.x-m); v.y=__expf(v.y-m); v.z=__expf(v.z-m); v.w=__expf(v.w-m);
    float s = v.x+v.y+v.z+v.w;
    s += __shfl_xor(s, 1);
    s += __shfl_xor(s, 2);
    s += __shfl_xor(s, 4);
    s += __shfl_xor(s, 8);
    float inv = 1.f/s;
    union{uint2 u; us h[4];} o;
    o.h[0]=f2bf(v.x*inv); o.h[1]=f2bf(v.y*inv); o.h[2]=f2bf(v.z*inv); o.h[3]=f2bf(v.w*inv);
    *(uint2*)&W[(size_t)head*4096 + d*64 + e0] = o.u;
}

// ---- M_{b,h}[nO,e] = sum_d wp[nO,h*64+d]*W[d,e]; 256 blocks (4 per head) ----
__launch_bounds__(256,2)
__global__ void fold(const us* __restrict__ Wsm, const us* __restrict__ wpbf,
                     us* __restrict__ Mcat){
    __shared__ us sWt[64*72];   // W^T: sWt[e][d]
    int t = threadIdx.x;
    int head = blockIdx.x>>2, part = blockIdx.x&3;
    int b = head>>3, h = head&7;
    int lane = t&63, w = t>>6, quad = lane>>4, l15 = lane&15;
    #pragma unroll
    for(int it=0; it<2; it++){
        int idx = it*2048 + t*8;
        int d = idx>>6, e0 = idx&63;
        union{uint4 v; us s[8];} q;
        q.v = *(const uint4*)&Wsm[(size_t)head*4096 + idx];
        #pragma unroll
        for(int j=0;j<8;j++) sWt[(e0+j)*72 + d] = q.s[j];
    }
    __syncthreads();
    #pragma unroll
    for(int i=0;i<2;i++){
        int nO = part*128 + w*32 + i*16 + l15;
        s16x8 af0 = *(const s16x8*)&wpbf[(size_t)nO*512 + h*64 + quad*8];
        s16x8 af1 = *(const s16x8*)&wpbf[(size_t)nO*512 + h*64 + 32 + quad*8];
        #pragma unroll
        for(int j=0;j<4;j++){
            s16x8 bf0 = *(const s16x8*)&sWt[(j*16+l15)*72 + quad*8];
            s16x8 bf1 = *(const s16x8*)&sWt[(j*16+l15)*72 + 32 + quad*8];
            f32x4 acc = (f32x4){0.f,0.f,0.f,0.f};
            acc = __builtin_amdgcn_mfma_f32_16x16x32_bf16(af0, bf0, acc, 0,0,0);
            acc = __builtin_amdgcn_mfma_f32_16x16x32_bf16(af1, bf1, acc, 0,0,0);
            #pragma unroll
            for(int r=0;r<4;r++){
                int row = part*128 + w*32 + i*16 + quad*4 + r;
                Mcat[((size_t)(b*512 + row))*512 + h*64 + j*16 + l15] = f2bf(acc[r]);
            }
        }
    }
}

// ==== out_b = Vgather_b @ Mcat_b^T + wp_b -- same 256^2 8-wave pipelined
// structure as gemm_qkv; K-tile kt == head kt. A is the flat-reinterp V gather:
// token n = mtb*256 + rho ; qkv row = b*4096 + kt*512 + mtb*32 + (rho>>3),
// col = 1024 + (rho&7)*64 + e  (rho&7 == l8 -> same XOR-swizzle key as reads).
__launch_bounds__(512,2)
__global__ void gemm_vout(const us* __restrict__ qkv, const us* __restrict__ Mcat,
                          const float* __restrict__ bias, float* __restrict__ out){
    __shared__ __attribute__((aligned(16))) us sA[2][16384];
    __shared__ __attribute__((aligned(16))) us sB[2][16384];
    int t = threadIdx.x;
    int id = blockIdx.x;                 // 256 = 8 XCD * 32
    int xcd = id & 7, s = id >> 3;
    int f = xcd*32 + s;
    int b = f>>5, rr = f&31, mtb = rr>>1, nt = rr&1;  // per batch: 16 Mt x 2 Nt
    int lane = t&63, wave = t>>6, quad = lane>>4, l15 = lane&15;
    int wm = wave>>2, wn = wave&3;
    int l8 = lane>>3;
    int sw = ((lane&7) ^ l8)*8;

    // per (round r, wave): one qkv row (b*4096 + kt*512 + mtb*32 + r*8 + wave),
    // 64 lanes cover its full 512-col V slice (swizzled 16B granules).
    const us* Ag = qkv + (size_t)(b*4096 + mtb*32 + wave)*1536 + 1024 + l8*64 + sw;
    // A: round r -> + r*8*1536 ; K-tile kt -> + kt*512*1536
    const us* Bg = Mcat + (size_t)(b*512 + nt*256 + wave*8 + l8)*512 + sw;
    // B: round r -> + r*64*512 ; K-tile kt -> + kt*64
    us* sA0 = &sA[0][0];
    us* sB0 = &sB[0][0];
    int wofs = wave*512;

    f32x4 acc[8][4];
    #pragma unroll
    for(int m=0;m<8;m++)
        #pragma unroll
        for(int n=0;n<4;n++) acc[m][n] = (f32x4){0.f,0.f,0.f,0.f};

    #pragma unroll
    for(int r=0;r<4;r++) glds16(Ag + r*12288, sA0 + wofs + r*4096);
    #pragma unroll
    for(int r=0;r<4;r++) glds16(Bg + r*32768, sB0 + wofs + r*4096);
    asm volatile("s_waitcnt vmcnt(0)" ::: "memory");
    __builtin_amdgcn_s_barrier();

    for(int kt=0; kt<8; ++kt){
        int cur = kt & 1;
        const us* sAc = sA0 + cur*16384;
        const us* sBc = sB0 + cur*16384;
        if(kt < 7){
            int nx = (cur^1)*16384 + wofs;
            size_t ka = (size_t)(kt+1)*786432;
            int kb2 = (kt+1)*64;
            #pragma unroll
            for(int r=0;r<4;r++) glds16(Ag + ka + r*12288, sA0 + nx + r*4096);
            #pragma unroll
            for(int r=0;r<4;r++) glds16(Bg + kb2 + r*32768, sB0 + nx + r*4096);
        }
        s16x8 bfr[4][2];
        #pragma unroll
        for(int n=0;n<4;n++){
            int rw = wn*64 + n*16 + l15;
            #pragma unroll
            for(int ks=0;ks<2;ks++){
                int kc = ks*4 + quad;
                bfr[n][ks] = *(const s16x8*)&sBc[rw*64 + ((kc ^ (rw&7))<<3)];
            }
        }
        #pragma unroll
        for(int p=0;p<4;p++){
            s16x8 af[2][2];
            #pragma unroll
            for(int i=0;i<2;i++){
                int rw = wm*128 + (2*p+i)*16 + l15;
                #pragma unroll
                for(int ks=0;ks<2;ks++){
                    int kc = ks*4 + quad;
                    af[i][ks] = *(const s16x8*)&sAc[rw*64 + ((kc ^ (rw&7))<<3)];
                }
            }
            __builtin_amdgcn_s_barrier();
            __builtin_amdgcn_s_setprio(1);
            #pragma unroll
            for(int ks=0;ks<2;ks++)
                #pragma unroll
                for(int i=0;i<2;i++)
                    #pragma unroll
                    for(int n=0;n<4;n++)
                        acc[2*p+i][n] = __builtin_amdgcn_mfma_f32_16x16x32_bf16(
                                            af[i][ks], bfr[n][ks], acc[2*p+i][n], 0,0,0);
            __builtin_amdgcn_s_setprio(0);
            __builtin_amdgcn_s_barrier();
        }
        if(kt < 7){
            asm volatile("s_waitcnt vmcnt(0)" ::: "memory");
            __builtin_amdgcn_s_barrier();
        }
    }

    int row0 = b*4096 + mtb*256 + wm*128;
    int col0 = nt*256 + wn*64;
    #pragma unroll
    for(int n=0;n<4;n++){
        int col = col0 + n*16 + l15;
        float bv = bias[col];
        #pragma unroll
        for(int m=0;m<8;m++){
            int rb = row0 + m*16 + quad*4;
            #pragma unroll
            for(int r2=0;r2<4;r2++)
                out[(size_t)(rb+r2)*512 + col] = acc[m][n][r2] + bv;
        }
    }
}

extern "C" void kernel_launch(void* const* d_in, const int* in_sizes, int n_in,
                              void* d_out, int out_size, void* d_ws, size_t ws_size,
                              hipStream_t stream){
    const float* x      = (const float*)d_in[0];
    const float* wqkv_w = (const float*)d_in[1];
    const float* wqkv_b = (const float*)d_in[2];
    const float* wp_w   = (const float*)d_in[3];
    const float* wp_b   = (const float*)d_in[4];

    char* ws = (char*)d_ws;
    us*    qkvbf  = (us*)(ws);                    // 96 MB
    us*    xbf    = (us*)(ws + 100663296);        // 32 MB
    float* Spart  = (float*)(ws + 134217728);     // 8 MB
    us*    Wsm    = (us*)(ws + 142606336);        // 0.5 MB
    us*    Mcat   = (us*)(ws + 143130624);        // 4 MB
    us*    wqkvbf = (us*)(ws + 147324928);        // 1.5 MB
    us*    wpbf   = (us*)(ws + 148897792);        // 0.5 MB

    cast_all<<<17408,256,0,stream>>>(x, wqkv_w, wp_w, xbf, wqkvbf, wpbf);

    gemm_qkv<<<768,512,0,stream>>>(xbf, wqkvbf, wqkv_b, qkvbf);

    attn_scores_mfma<<<dim3(8,64),256,0,stream>>>(qkvbf, Spart);
    softmax64<<<256,256,0,stream>>>(Spart, Wsm);
    fold<<<256,256,0,stream>>>(Wsm, wpbf, Mcat);

    gemm_vout<<<256,512,0,stream>>>(qkvbf, Mcat, wp_b, (float*)d_out);
}

// Round 3
// 256.545 us; speedup vs baseline: 1.0237x; 1.0237x over previous
//
#include <hip/hip_runtime.h>

typedef short s16x8 __attribute__((ext_vector_type(8)));
typedef float f32x4 __attribute__((ext_vector_type(4)));
typedef unsigned short us;

__device__ inline us f2bf(float f){
    union{float f;unsigned u;} v{f};
    unsigned r = v.u + 0x7fff + ((v.u>>16)&1);
    return (us)(r>>16);
}

__device__ __forceinline__ void glds16(const us* g, us* l){
    __builtin_amdgcn_global_load_lds(
        (const __attribute__((address_space(1))) unsigned int*)(g),
        (__attribute__((address_space(3))) unsigned int*)(l), 16, 0, 0);
}

// ---------------- fused cast: x, wqkv_w, wp_w -> bf16, one launch ----------------
__global__ void cast_all(const float* __restrict__ x, const float* __restrict__ wqkv_w,
                         const float* __restrict__ wp_w, us* __restrict__ xbf,
                         us* __restrict__ wqkvbf, us* __restrict__ wpbf){
    int i = blockIdx.x*blockDim.x + threadIdx.x;   // 4456448 float4s
    const float* s; us* d; int j;
    if(i < 4194304){ s = x; d = xbf; j = i; }
    else if(i < 4390912){ s = wqkv_w; d = wqkvbf; j = i - 4194304; }
    else { s = wp_w; d = wpbf; j = i - 4390912; }
    float4 f = ((const float4*)s)[j];
    ushort4 o;
    o.x = f2bf(f.x); o.y = f2bf(f.y); o.z = f2bf(f.z); o.w = f2bf(f.w);
    ((ushort4*)d)[j] = o;
}

// ==== qkv = xbf @ wqkv^T + b  (M=32768,N=1536,K=512) ====
// 256x256 tile, 8 waves (2M x 4N), BK=64, dbuf LDS (128 KiB).
// Fine-interleaved 4-phase/K-tile schedule (m201/T3+T4 recipe): each phase
// { ds_read subtile ; 2x glds16 prefetch ; counted vmcnt ; s_barrier ;
//   setprio(1) ; 16 MFMA ; setprio(0) ; s_barrier }.
// Stage rounds aligned with phase reads so vmcnt(4) (never 0 in steady state)
// guarantees exactly the LDS rows the next phase needs, for every wave.
// MFMA operands SWAPPED so lanes hold 4 consecutive output cols -> ushort4
// stores (fixes the 188MB write amplification seen with 2B scalar stores).
__launch_bounds__(512,2)
__global__ void gemm_qkv(const us* __restrict__ A, const us* __restrict__ B,
                         const float* __restrict__ bias, us* __restrict__ C){
    __shared__ __attribute__((aligned(16))) us sA[2][16384];
    __shared__ __attribute__((aligned(16))) us sB[2][16384];
    int t = threadIdx.x;
    int id = blockIdx.x;                 // 768 = 8 XCD * 96 (bijective swizzle)
    int xcd = id & 7, s = id >> 3;
    int nt = s % 6, mt = xcd*16 + s/6;   // Mt=128, Nt=6
    int lane = t&63, w = t>>6, quad = lane>>4, l15 = lane&15;
    int wm = w>>2, wn = w&3;             // wave tile: 128 rows x 64 cols
    int l8 = lane>>3;
    int sw = ((lane&7) ^ l8)*8;          // pre-swizzled global source (rule #21)

    // stage-round row bases: A round r covers rows {wm*128 + r*32 + (w&3)*8 + l8},
    // B round r covers rows {(w>>1)*64 + r*16 + (w&1)*8 + l8} -- each round pair
    // = exactly the rows one future phase reads, across ALL waves.
    int rA0 = wm*128 + (w&3)*8;
    int rB0 = (w>>1)*64 + (w&1)*8;
    const us* Ag = A + (size_t)(mt*256 + rA0 + l8)*512 + sw;
    const us* Bg = B + (size_t)(nt*256 + rB0 + l8)*512 + sw;
    us* sA0 = &sA[0][0];
    us* sB0 = &sB[0][0];
    int aofs = rA0*64, bofs = rB0*64;

#define STA(r,kt,bo) glds16(Ag + (size_t)(r)*16384 + (size_t)(kt)*64, sA0 + (bo) + aofs + (r)*2048)
#define STB(r,kt,bo) glds16(Bg + (size_t)(r)*8192  + (size_t)(kt)*64, sB0 + (bo) + bofs + (r)*1024)

    f32x4 acc[8][4];
    #pragma unroll
    for(int m=0;m<8;m++)
        #pragma unroll
        for(int n=0;n<4;n++) acc[m][n] = (f32x4){0.f,0.f,0.f,0.f};

    // prologue: tile 0 -> buf0, in the canonical round order A0,A1,B0,B1,B2,B3,A2,A3
    STA(0,0,0); STA(1,0,0); STB(0,0,0); STB(1,0,0);
    STB(2,0,0); STB(3,0,0); STA(2,0,0); STA(3,0,0);
    asm volatile("s_waitcnt vmcnt(4)" ::: "memory");   // A0,A1,B0,B1 landed
    __builtin_amdgcn_s_barrier();

    s16x8 aF[4][2], bF[4][2];
    for(int kt=0; kt<8; ++kt){
        int co = (kt&1)*16384, no = co^16384;
        const us* sAc = sA0 + co;
        const us* sBc = sB0 + co;

        // ---- ph0: read A m0-3 + B n0-1 ; stage A-r0,A-r1 ; vmcnt(4) ----
        #pragma unroll
        for(int i=0;i<4;i++){
            int rw = wm*128 + i*16 + l15;
            #pragma unroll
            for(int ks=0;ks<2;ks++){
                int kc = ks*4 + quad;
                aF[i][ks] = *(const s16x8*)&sAc[rw*64 + ((kc ^ (rw&7))<<3)];
            }
        }
        #pragma unroll
        for(int n=0;n<2;n++){
            int rw = wn*64 + n*16 + l15;
            #pragma unroll
            for(int ks=0;ks<2;ks++){
                int kc = ks*4 + quad;
                bF[n][ks] = *(const s16x8*)&sBc[rw*64 + ((kc ^ (rw&7))<<3)];
            }
        }
        if(kt<7){ STA(0,kt+1,no); STA(1,kt+1,no);
                  asm volatile("s_waitcnt vmcnt(4)" ::: "memory"); }
        else    { asm volatile("s_waitcnt vmcnt(2)" ::: "memory"); }
        __builtin_amdgcn_s_barrier();
        __builtin_amdgcn_s_setprio(1);
        #pragma unroll
        for(int ks=0;ks<2;ks++)
            #pragma unroll
            for(int i=0;i<4;i++)
                #pragma unroll
                for(int n=0;n<2;n++)
                    acc[i][n] = __builtin_amdgcn_mfma_f32_16x16x32_bf16(bF[n][ks], aF[i][ks], acc[i][n], 0,0,0);
        __builtin_amdgcn_s_setprio(0);
        __builtin_amdgcn_s_barrier();

        // ---- ph1: read B n2-3 ; stage B-r0,B-r1 ; vmcnt(4) ----
        #pragma unroll
        for(int n=2;n<4;n++){
            int rw = wn*64 + n*16 + l15;
            #pragma unroll
            for(int ks=0;ks<2;ks++){
                int kc = ks*4 + quad;
                bF[n][ks] = *(const s16x8*)&sBc[rw*64 + ((kc ^ (rw&7))<<3)];
            }
        }
        if(kt<7){ STB(0,kt+1,no); STB(1,kt+1,no);
                  asm volatile("s_waitcnt vmcnt(4)" ::: "memory"); }
        else    { asm volatile("s_waitcnt vmcnt(0)" ::: "memory"); }
        __builtin_amdgcn_s_barrier();
        __builtin_amdgcn_s_setprio(1);
        #pragma unroll
        for(int ks=0;ks<2;ks++)
            #pragma unroll
            for(int i=0;i<4;i++)
                #pragma unroll
                for(int n=2;n<4;n++)
                    acc[i][n] = __builtin_amdgcn_mfma_f32_16x16x32_bf16(bF[n][ks], aF[i][ks], acc[i][n], 0,0,0);
        __builtin_amdgcn_s_setprio(0);
        __builtin_amdgcn_s_barrier();

        // ---- ph2: read A m4-7 ; stage B-r2,B-r3 ; (no wait needed) ----
        #pragma unroll
        for(int i=0;i<4;i++){
            int rw = wm*128 + (4+i)*16 + l15;
            #pragma unroll
            for(int ks=0;ks<2;ks++){
                int kc = ks*4 + quad;
                aF[i][ks] = *(const s16x8*)&sAc[rw*64 + ((kc ^ (rw&7))<<3)];
            }
        }
        if(kt<7){ STB(2,kt+1,no); STB(3,kt+1,no); }
        __builtin_amdgcn_s_barrier();
        __builtin_amdgcn_s_setprio(1);
        #pragma unroll
        for(int ks=0;ks<2;ks++)
            #pragma unroll
            for(int i=0;i<4;i++)
                #pragma unroll
                for(int n=0;n<2;n++)
                    acc[4+i][n] = __builtin_amdgcn_mfma_f32_16x16x32_bf16(bF[n][ks], aF[i][ks], acc[4+i][n], 0,0,0);
        __builtin_amdgcn_s_setprio(0);
        __builtin_amdgcn_s_barrier();

        // ---- ph3: stage A-r2,A-r3 ; vmcnt(4) guards next tile's ph0 ----
        if(kt<7){ STA(2,kt+1,no); STA(3,kt+1,no);
                  asm volatile("s_waitcnt vmcnt(4)" ::: "memory"); }
        __builtin_amdgcn_s_barrier();
        __builtin_amdgcn_s_setprio(1);
        #pragma unroll
        for(int ks=0;ks<2;ks++)
            #pragma unroll
            for(int i=0;i<4;i++)
                #pragma unroll
                for(int n=2;n<4;n++)
                    acc[4+i][n] = __builtin_amdgcn_mfma_f32_16x16x32_bf16(bF[n][ks], aF[i][ks], acc[4+i][n], 0,0,0);
        __builtin_amdgcn_s_setprio(0);
        __builtin_amdgcn_s_barrier();
    }
#undef STA
#undef STB

    // epilogue: swapped layout -> lane holds rows m*16+l15, cols n*16+quad*4..+3
    int row0 = mt*256 + wm*128, col0 = nt*256 + wn*64;
    float4 bv[4];
    #pragma unroll
    for(int n=0;n<4;n++) bv[n] = *(const float4*)&bias[col0 + n*16 + quad*4];
    #pragma unroll
    for(int m=0;m<8;m++){
        size_t rb = (size_t)(row0 + m*16 + l15)*1536 + col0;
        #pragma unroll
        for(int n=0;n<4;n++){
            ushort4 o;
            o.x = f2bf(acc[m][n][0] + bv[n].x);
            o.y = f2bf(acc[m][n][1] + bv[n].y);
            o.z = f2bf(acc[m][n][2] + bv[n].z);
            o.w = f2bf(acc[m][n][3] + bv[n].w);
            *(ushort4*)&C[rb + n*16 + quad*4] = o;
        }
    }
}

// ---- scores: Spart[kb][head][d][e] = partial over 512 tokens (kb<8, 8 chunks) ----
__launch_bounds__(256,4)
__global__ void attn_scores_mfma(const us* __restrict__ qkv, float* __restrict__ Sp){
    __shared__ __attribute__((aligned(16))) us sQt[64*72];
    __shared__ __attribute__((aligned(16))) us sKt[64*72];
    int t = threadIdx.x;
    int kb = blockIdx.x, head = blockIdx.y;   // kb < 8
    int lane = t & 63, w = t >> 6;
    int quad = lane >> 4, l15 = lane & 15;
    int p = t & 31;
    int d0 = (t >> 5) * 8;

    f32x4 acc[4];
    #pragma unroll
    for(int j=0;j<4;j++) acc[j] = (f32x4){0.f,0.f,0.f,0.f};

    for(int chunk=0; chunk<8; chunk++){
        int r0 = head*512 + kb*64 + chunk*8;
        const us* g = qkv + (size_t)(r0 + (p>>2))*1536 + (2*(p&3))*64 + d0;
        union{uint4 v; us h[8];} q0, q1, k0, k1;
        q0.v = *(const uint4*)g;         q1.v = *(const uint4*)(g + 64);
        k0.v = *(const uint4*)(g + 512); k1.v = *(const uint4*)(g + 576);
        #pragma unroll
        for(int j=0;j<8;j++){
            *(unsigned*)&sQt[(d0+j)*72 + 2*p] = (unsigned)q0.h[j] | ((unsigned)q1.h[j]<<16);
            *(unsigned*)&sKt[(d0+j)*72 + 2*p] = (unsigned)k0.h[j] | ((unsigned)k1.h[j]<<16);
        }
        __syncthreads();
        int d = w*16 + l15;
        #pragma unroll
        for(int ks=0; ks<2; ks++){
            int tb = ks*4 + quad;
            s16x8 af = *(const s16x8*)&sQt[d*72 + tb*8];
            #pragma unroll
            for(int jt=0; jt<4; jt++){
                int e = jt*16 + l15;
                s16x8 bfv = *(const s16x8*)&sKt[e*72 + tb*8];
                acc[jt] = __builtin_amdgcn_mfma_f32_16x16x32_bf16(af, bfv, acc[jt], 0,0,0);
            }
        }
        __syncthreads();
    }

    float* S = Sp + (size_t)(kb*64 + head)*4096;
    #pragma unroll
    for(int jt=0; jt<4; jt++){
        int e = jt*16 + l15;
        #pragma unroll
        for(int r=0; r<4; r++){
            int d = w*16 + quad*4 + r;
            S[d*64 + e] = acc[jt][r];
        }
    }
}

// ---- sum 8 partials, softmax over e (scale 1/8); 256 blocks (4 d-strips/head) ----
__global__ void softmax64(const float* __restrict__ Sp, us* __restrict__ W){
    int head = blockIdx.x>>2, part = blockIdx.x&3;
    int t = threadIdx.x;           // 256
    int d = part*16 + (t>>4), e0 = (t&15)*4;
    float4 v = {0.f,0.f,0.f,0.f};
    for(int kb=0; kb<8; kb++){
        float4 f = *(const float4*)&Sp[(size_t)(kb*64 + head)*4096 + d*64 + e0];
        v.x+=f.x; v.y+=f.y; v.z+=f.z; v.w+=f.w;
    }
    v.x*=0.125f; v.y*=0.125f; v.z*=0.125f; v.w*=0.125f;
    float m = fmaxf(fmaxf(v.x,v.y), fmaxf(v.z,v.w));
    m = fmaxf(m, __shfl_xor(m, 1));
    m = fmaxf(m, __shfl_xor(m, 2));
    m = fmaxf(m, __shfl_xor(m, 4));
    m = fmaxf(m, __shfl_xor(m, 8));
    v.x=__expf(v.x-m); v.y=__expf(v.y-m); v.z=__expf(v.z-m); v.w=__expf(v.w-m);
    float s = v.x+v.y+v.z+v.w;
    s += __shfl_xor(s, 1);
    s += __shfl_xor(s, 2);
    s += __shfl_xor(s, 4);
    s += __shfl_xor(s, 8);
    float inv = 1.f/s;
    union{uint2 u; us h[4];} o;
    o.h[0]=f2bf(v.x*inv); o.h[1]=f2bf(v.y*inv); o.h[2]=f2bf(v.z*inv); o.h[3]=f2bf(v.w*inv);
    *(uint2*)&W[(size_t)head*4096 + d*64 + e0] = o.u;
}

// ---- M_{b,h}[nO,e] = sum_d wp[nO,h*64+d]*W[d,e]; 256 blocks (4 per head) ----
__launch_bounds__(256,2)
__global__ void fold(const us* __restrict__ Wsm, const us* __restrict__ wpbf,
                     us* __restrict__ Mcat){
    __shared__ us sWt[64*72];   // W^T: sWt[e][d]
    int t = threadIdx.x;
    int head = blockIdx.x>>2, part = blockIdx.x&3;
    int b = head>>3, h = head&7;
    int lane = t&63, w = t>>6, quad = lane>>4, l15 = lane&15;
    #pragma unroll
    for(int it=0; it<2; it++){
        int idx = it*2048 + t*8;
        int d = idx>>6, e0 = idx&63;
        union{uint4 v; us s[8];} q;
        q.v = *(const uint4*)&Wsm[(size_t)head*4096 + idx];
        #pragma unroll
        for(int j=0;j<8;j++) sWt[(e0+j)*72 + d] = q.s[j];
    }
    __syncthreads();
    #pragma unroll
    for(int i=0;i<2;i++){
        int nO = part*128 + w*32 + i*16 + l15;
        s16x8 af0 = *(const s16x8*)&wpbf[(size_t)nO*512 + h*64 + quad*8];
        s16x8 af1 = *(const s16x8*)&wpbf[(size_t)nO*512 + h*64 + 32 + quad*8];
        #pragma unroll
        for(int j=0;j<4;j++){
            s16x8 bf0 = *(const s16x8*)&sWt[(j*16+l15)*72 + quad*8];
            s16x8 bf1 = *(const s16x8*)&sWt[(j*16+l15)*72 + 32 + quad*8];
            f32x4 acc = (f32x4){0.f,0.f,0.f,0.f};
            acc = __builtin_amdgcn_mfma_f32_16x16x32_bf16(af0, bf0, acc, 0,0,0);
            acc = __builtin_amdgcn_mfma_f32_16x16x32_bf16(af1, bf1, acc, 0,0,0);
            #pragma unroll
            for(int r=0;r<4;r++){
                int row = part*128 + w*32 + i*16 + quad*4 + r;
                Mcat[((size_t)(b*512 + row))*512 + h*64 + j*16 + l15] = f2bf(acc[r]);
            }
        }
    }
}

// ---- out_b = Vgather_b @ Mcat_b^T + wp_b. BK=64 (one head per iter), swizzled. ----
__launch_bounds__(256,4)
__global__ void gemm_vout(const us* __restrict__ qkv, const us* __restrict__ Mcat,
                          const float* __restrict__ bias, float* __restrict__ out){
    __shared__ __attribute__((aligned(16))) us sA[128*64];
    __shared__ __attribute__((aligned(16))) us sB[128*64];
    int t = threadIdx.x;
    int id = blockIdx.x;                 // 1024
    int xcd = id & 7, s = id >> 3;
    int nt = s & 3, mt = xcd*32 + (s>>2);
    int b = mt>>5, mr = mt&31;
    int lane = t&63, wave = t>>6, quad = lane>>4, l15 = lane&15;
    int wm = wave>>1, wn = wave&1;

    int l8 = lane>>3;
    int sw = ((lane&7) ^ l8)*8;
    const us* Abase = qkv + ((size_t)(8*b)*512 + mr*16 + wave*4)*1536 + 1024 + l8*64 + sw;
    const us* Bbase = Mcat + ((size_t)(b*512 + nt*128 + wave*32 + l8))*512 + sw;
    us* sAw = &sA[(wave*32)*64];
    us* sBw = &sB[(wave*32)*64];

    f32x4 acc[4][4];
    #pragma unroll
    for(int i=0;i<4;i++)
        #pragma unroll
        for(int j=0;j<4;j++) acc[i][j] = (f32x4){0.f,0.f,0.f,0.f};

    for(int h=0; h<8; h++){
        const us* Ah = Abase + (size_t)h*512*1536;
        const us* Bh = Bbase + h*64;
        glds16(Ah,           sAw);
        glds16(Ah + 1536,    sAw + 8*64);
        glds16(Ah + 2*1536,  sAw + 16*64);
        glds16(Ah + 3*1536,  sAw + 24*64);
        glds16(Bh,           sBw);
        glds16(Bh + 8*512,   sBw + 8*64);
        glds16(Bh + 16*512,  sBw + 16*64);
        glds16(Bh + 24*512,  sBw + 24*64);
        __syncthreads();
        #pragma unroll
        for(int ks=0; ks<2; ks++){
            int kc = ks*4 + quad;
            s16x8 af[4], bfr[4];
            #pragma unroll
            for(int i=0;i<4;i++){
                int r = wm*64 + i*16 + l15;
                af[i] = *(const s16x8*)&sA[r*64 + ((kc ^ (r&7))<<3)];
            }
            #pragma unroll
            for(int j=0;j<4;j++){
                int r = wn*64 + j*16 + l15;
                bfr[j] = *(const s16x8*)&sB[r*64 + ((kc ^ (r&7))<<3)];
            }
            #pragma unroll
            for(int i=0;i<4;i++)
                #pragma unroll
                for(int j=0;j<4;j++)
                    acc[i][j] = __builtin_amdgcn_mfma_f32_16x16x32_bf16(af[i], bfr[j], acc[i][j], 0,0,0);
        }
        __syncthreads();
    }

    int row0 = b*4096 + mr*128 + wm*64;
    int col0 = nt*128 + wn*64;
    #pragma unroll
    for(int j=0;j<4;j++){
        int col = col0 + j*16 + l15;
        float bv = bias[col];
        #pragma unroll
        for(int i=0;i<4;i++){
            int rbase = row0 + i*16 + quad*4;
            #pragma unroll
            for(int r2=0;r2<4;r2++)
                out[(size_t)(rbase+r2)*512 + col] = acc[i][j][r2] + bv;
        }
    }
}

extern "C" void kernel_launch(void* const* d_in, const int* in_sizes, int n_in,
                              void* d_out, int out_size, void* d_ws, size_t ws_size,
                              hipStream_t stream){
    const float* x      = (const float*)d_in[0];
    const float* wqkv_w = (const float*)d_in[1];
    const float* wqkv_b = (const float*)d_in[2];
    const float* wp_w   = (const float*)d_in[3];
    const float* wp_b   = (const float*)d_in[4];

    char* ws = (char*)d_ws;
    us*    qkvbf  = (us*)(ws);                    // 96 MB
    us*    xbf    = (us*)(ws + 100663296);        // 32 MB
    float* Spart  = (float*)(ws + 134217728);     // 8 MB
    us*    Wsm    = (us*)(ws + 142606336);        // 0.5 MB
    us*    Mcat   = (us*)(ws + 143130624);        // 4 MB
    us*    wqkvbf = (us*)(ws + 147324928);        // 1.5 MB
    us*    wpbf   = (us*)(ws + 148897792);        // 0.5 MB

    cast_all<<<17408,256,0,stream>>>(x, wqkv_w, wp_w, xbf, wqkvbf, wpbf);

    gemm_qkv<<<768,512,0,stream>>>(xbf, wqkvbf, wqkv_b, qkvbf);

    attn_scores_mfma<<<dim3(8,64),256,0,stream>>>(qkvbf, Spart);
    softmax64<<<256,256,0,stream>>>(Spart, Wsm);
    fold<<<256,256,0,stream>>>(Wsm, wpbf, Mcat);

    gemm_vout<<<1024,256,0,stream>>>(qkvbf, Mcat, wp_b, (float*)d_out);
}

// Round 4
// 242.634 us; speedup vs baseline: 1.0824x; 1.0573x over previous
//
#include <hip/hip_runtime.h>

typedef short s16x8 __attribute__((ext_vector_type(8)));
typedef float f32x4 __attribute__((ext_vector_type(4)));
typedef unsigned short us;

__device__ inline us f2bf(float f){
    union{float f;unsigned u;} v{f};
    unsigned r = v.u + 0x7fff + ((v.u>>16)&1);
    return (us)(r>>16);
}

__device__ __forceinline__ void glds16(const us* g, us* l){
    __builtin_amdgcn_global_load_lds(
        (const __attribute__((address_space(1))) unsigned int*)(g),
        (__attribute__((address_space(3))) unsigned int*)(l), 16, 0, 0);
}

// ---------------- fused cast: x, wqkv_w, wp_w -> bf16, one launch ----------------
__global__ void cast_all(const float* __restrict__ x, const float* __restrict__ wqkv_w,
                         const float* __restrict__ wp_w, us* __restrict__ xbf,
                         us* __restrict__ wqkvbf, us* __restrict__ wpbf){
    int i = blockIdx.x*blockDim.x + threadIdx.x;   // 4456448 float4s
    const float* s; us* d; int j;
    if(i < 4194304){ s = x; d = xbf; j = i; }
    else if(i < 4390912){ s = wqkv_w; d = wqkvbf; j = i - 4194304; }
    else { s = wp_w; d = wpbf; j = i - 4390912; }
    float4 f = ((const float4*)s)[j];
    ushort4 o;
    o.x = f2bf(f.x); o.y = f2bf(f.y); o.z = f2bf(f.z); o.w = f2bf(f.w);
    ((ushort4*)d)[j] = o;
}

// ---- qkv = xbf @ wqkv^T + b  (M=32768,N=1536,K=512). Round-0 128x128 structure
// (verified 74.9us, 4 blocks/CU TLP) + swapped-operand MFMA so each lane holds 4
// consecutive output cols -> ushort4 stores (verified in round 3). ----
__launch_bounds__(256,4)
__global__ void gemm_qkv(const us* __restrict__ A, const us* __restrict__ B,
                         const float* __restrict__ bias, us* __restrict__ C){
    __shared__ __attribute__((aligned(16))) us sA[128*64];
    __shared__ __attribute__((aligned(16))) us sB[128*64];
    int t = threadIdx.x;
    int id = blockIdx.x;                 // 3072
    int xcd = id & 7, s = id >> 3;
    int nt = s % 12, mt = xcd*32 + s/12;
    int lane = t&63, wave = t>>6, quad = lane>>4, l15 = lane&15;
    int wm = wave>>1, wn = wave&1;

    int l8 = lane>>3;
    int sw = ((lane&7) ^ l8)*8;
    const us* Ag = A + (size_t)(mt*128 + wave*32 + l8)*512 + sw;
    const us* Bg = B + (size_t)(nt*128 + wave*32 + l8)*512 + sw;
    us* sAw = &sA[(wave*32)*64];
    us* sBw = &sB[(wave*32)*64];

    f32x4 acc[4][4];
    #pragma unroll
    for(int i=0;i<4;i++)
        #pragma unroll
        for(int j=0;j<4;j++) acc[i][j] = (f32x4){0.f,0.f,0.f,0.f};

    for(int k0=0; k0<512; k0+=64){
        glds16(Ag + k0,           sAw);
        glds16(Ag + 8*512 + k0,   sAw + 8*64);
        glds16(Ag + 16*512 + k0,  sAw + 16*64);
        glds16(Ag + 24*512 + k0,  sAw + 24*64);
        glds16(Bg + k0,           sBw);
        glds16(Bg + 8*512 + k0,   sBw + 8*64);
        glds16(Bg + 16*512 + k0,  sBw + 16*64);
        glds16(Bg + 24*512 + k0,  sBw + 24*64);
        __syncthreads();
        #pragma unroll
        for(int ks=0; ks<2; ks++){
            int kc = ks*4 + quad;
            s16x8 af[4], bfr[4];
            #pragma unroll
            for(int i=0;i<4;i++){
                int r = wm*64 + i*16 + l15;
                af[i] = *(const s16x8*)&sA[r*64 + ((kc ^ (r&7))<<3)];
            }
            #pragma unroll
            for(int j=0;j<4;j++){
                int r = wn*64 + j*16 + l15;
                bfr[j] = *(const s16x8*)&sB[r*64 + ((kc ^ (r&7))<<3)];
            }
            #pragma unroll
            for(int i=0;i<4;i++)
                #pragma unroll
                for(int j=0;j<4;j++)
                    acc[i][j] = __builtin_amdgcn_mfma_f32_16x16x32_bf16(bfr[j], af[i], acc[i][j], 0,0,0);
        }
        __syncthreads();
    }

    // swapped layout: lane holds row = row0+i*16+l15, cols = col0+j*16+quad*4..+3
    int row0 = mt*128 + wm*64, col0 = nt*128 + wn*64;
    float4 bv[4];
    #pragma unroll
    for(int j=0;j<4;j++) bv[j] = *(const float4*)&bias[col0 + j*16 + quad*4];
    #pragma unroll
    for(int i=0;i<4;i++){
        size_t rb = (size_t)(row0 + i*16 + l15)*1536 + col0;
        #pragma unroll
        for(int j=0;j<4;j++){
            ushort4 o;
            o.x = f2bf(acc[i][j][0] + bv[j].x);
            o.y = f2bf(acc[i][j][1] + bv[j].y);
            o.z = f2bf(acc[i][j][2] + bv[j].z);
            o.w = f2bf(acc[i][j][3] + bv[j].w);
            *(ushort4*)&C[rb + j*16 + quad*4] = o;
        }
    }
}

// ---- scores: Spart[kb][head][d][e] partial over 512 tokens. T14 async-split:
// chunk c+1's global loads issued before chunk c's LDS-write/compute (regs
// double-buffered, full unroll -> static indexing). ----
__launch_bounds__(256,4)
__global__ void attn_scores_mfma(const us* __restrict__ qkv, float* __restrict__ Sp){
    __shared__ __attribute__((aligned(16))) us sQt[64*72];
    __shared__ __attribute__((aligned(16))) us sKt[64*72];
    int t = threadIdx.x;
    int kb = blockIdx.x, head = blockIdx.y;   // kb < 8
    int lane = t & 63, w = t >> 6;
    int quad = lane >> 4, l15 = lane & 15;
    int p = t & 31;
    int d0 = (t >> 5) * 8;

    f32x4 acc[4];
    #pragma unroll
    for(int j=0;j<4;j++) acc[j] = (f32x4){0.f,0.f,0.f,0.f};

    const us* gbase = qkv + (size_t)(head*512 + kb*64 + (p>>2))*1536 + (2*(p&3))*64 + d0;
    union U{uint4 v; us h[8];};
    U q0,q1,k0,k1, nq0,nq1,nk0,nk1;
    q0.v = *(const uint4*)gbase;         q1.v = *(const uint4*)(gbase + 64);
    k0.v = *(const uint4*)(gbase + 512); k1.v = *(const uint4*)(gbase + 576);

    #pragma unroll
    for(int c=0; c<8; c++){
        if(c<7){
            const us* g = gbase + (size_t)(c+1)*8*1536;
            nq0.v = *(const uint4*)g;         nq1.v = *(const uint4*)(g + 64);
            nk0.v = *(const uint4*)(g + 512); nk1.v = *(const uint4*)(g + 576);
        }
        #pragma unroll
        for(int j=0;j<8;j++){
            *(unsigned*)&sQt[(d0+j)*72 + 2*p] = (unsigned)q0.h[j] | ((unsigned)q1.h[j]<<16);
            *(unsigned*)&sKt[(d0+j)*72 + 2*p] = (unsigned)k0.h[j] | ((unsigned)k1.h[j]<<16);
        }
        __syncthreads();
        int d = w*16 + l15;
        #pragma unroll
        for(int ks=0; ks<2; ks++){
            int tb = ks*4 + quad;
            s16x8 af = *(const s16x8*)&sQt[d*72 + tb*8];
            #pragma unroll
            for(int jt=0; jt<4; jt++){
                s16x8 bfv = *(const s16x8*)&sKt[(jt*16+l15)*72 + tb*8];
                acc[jt] = __builtin_amdgcn_mfma_f32_16x16x32_bf16(af, bfv, acc[jt], 0,0,0);
            }
        }
        __syncthreads();
        q0 = nq0; q1 = nq1; k0 = nk0; k1 = nk1;
    }

    float* S = Sp + (size_t)(kb*64 + head)*4096;
    #pragma unroll
    for(int jt=0; jt<4; jt++){
        int e = jt*16 + l15;
        #pragma unroll
        for(int r=0; r<4; r++){
            int d = w*16 + quad*4 + r;
            S[d*64 + e] = acc[jt][r];
        }
    }
}

// ---- fused softmax+fold: 256 blocks (head,part). Each block computes its head's
// full 64x64 softmax (redundant across the 4 parts; Spart is L2/L3-resident)
// straight into LDS (transposed, bf16), then does its fold quarter. ----
__launch_bounds__(256,2)
__global__ void softfold(const float* __restrict__ Sp, const us* __restrict__ wpbf,
                         us* __restrict__ Mcat){
    __shared__ us sWt[64*72];   // W^T: sWt[e][d]
    int t = threadIdx.x;
    int head = blockIdx.x>>2, part = blockIdx.x&3;
    int b = head>>3, h = head&7;
    int lane = t&63, w = t>>6, quad = lane>>4, l15 = lane&15;

    // --- softmax over e for all 64 d-rows: thread t handles row d=t>>2, 16 e's ---
    int d = t>>2, e0 = (t&3)*16;
    float vv[16];
    #pragma unroll
    for(int j=0;j<16;j++) vv[j] = 0.f;
    for(int kb=0; kb<8; kb++){
        const float4* pp = (const float4*)&Sp[(size_t)(kb*64 + head)*4096 + d*64 + e0];
        #pragma unroll
        for(int q=0;q<4;q++){
            float4 g = pp[q];
            vv[4*q+0]+=g.x; vv[4*q+1]+=g.y; vv[4*q+2]+=g.z; vv[4*q+3]+=g.w;
        }
    }
    float m = -1e30f;
    #pragma unroll
    for(int j=0;j<16;j++){ vv[j] *= 0.125f; m = fmaxf(m, vv[j]); }
    m = fmaxf(m, __shfl_xor(m, 1));
    m = fmaxf(m, __shfl_xor(m, 2));
    float ssum = 0.f;
    #pragma unroll
    for(int j=0;j<16;j++){ vv[j] = __expf(vv[j]-m); ssum += vv[j]; }
    ssum += __shfl_xor(ssum, 1);
    ssum += __shfl_xor(ssum, 2);
    float inv = 1.f/ssum;
    #pragma unroll
    for(int j=0;j<16;j++) sWt[(e0+j)*72 + d] = f2bf(vv[j]*inv);
    __syncthreads();

    // --- fold quarter: M[nO,e] = sum_d wp[nO,h*64+d]*W[d,e] ---
    #pragma unroll
    for(int i=0;i<2;i++){
        int nO = part*128 + w*32 + i*16 + l15;
        s16x8 af0 = *(const s16x8*)&wpbf[(size_t)nO*512 + h*64 + quad*8];
        s16x8 af1 = *(const s16x8*)&wpbf[(size_t)nO*512 + h*64 + 32 + quad*8];
        #pragma unroll
        for(int j=0;j<4;j++){
            s16x8 bf0 = *(const s16x8*)&sWt[(j*16+l15)*72 + quad*8];
            s16x8 bf1 = *(const s16x8*)&sWt[(j*16+l15)*72 + 32 + quad*8];
            f32x4 acc = (f32x4){0.f,0.f,0.f,0.f};
            acc = __builtin_amdgcn_mfma_f32_16x16x32_bf16(af0, bf0, acc, 0,0,0);
            acc = __builtin_amdgcn_mfma_f32_16x16x32_bf16(af1, bf1, acc, 0,0,0);
            #pragma unroll
            for(int r=0;r<4;r++){
                int row = part*128 + w*32 + i*16 + quad*4 + r;
                Mcat[((size_t)(b*512 + row))*512 + h*64 + j*16 + l15] = f2bf(acc[r]);
            }
        }
    }
}

// ---- out_b = Vgather_b @ Mcat_b^T + wp_b. Round-0 structure + swapped MFMA
// epilogue -> float4 stores. ----
__launch_bounds__(256,4)
__global__ void gemm_vout(const us* __restrict__ qkv, const us* __restrict__ Mcat,
                          const float* __restrict__ bias, float* __restrict__ out){
    __shared__ __attribute__((aligned(16))) us sA[128*64];
    __shared__ __attribute__((aligned(16))) us sB[128*64];
    int t = threadIdx.x;
    int id = blockIdx.x;                 // 1024
    int xcd = id & 7, s = id >> 3;
    int nt = s & 3, mt = xcd*32 + (s>>2);
    int b = mt>>5, mr = mt&31;
    int lane = t&63, wave = t>>6, quad = lane>>4, l15 = lane&15;
    int wm = wave>>1, wn = wave&1;

    int l8 = lane>>3;
    int sw = ((lane&7) ^ l8)*8;
    const us* Abase = qkv + ((size_t)(8*b)*512 + mr*16 + wave*4)*1536 + 1024 + l8*64 + sw;
    const us* Bbase = Mcat + ((size_t)(b*512 + nt*128 + wave*32 + l8))*512 + sw;
    us* sAw = &sA[(wave*32)*64];
    us* sBw = &sB[(wave*32)*64];

    f32x4 acc[4][4];
    #pragma unroll
    for(int i=0;i<4;i++)
        #pragma unroll
        for(int j=0;j<4;j++) acc[i][j] = (f32x4){0.f,0.f,0.f,0.f};

    for(int h=0; h<8; h++){
        const us* Ah = Abase + (size_t)h*512*1536;
        const us* Bh = Bbase + h*64;
        glds16(Ah,           sAw);
        glds16(Ah + 1536,    sAw + 8*64);
        glds16(Ah + 2*1536,  sAw + 16*64);
        glds16(Ah + 3*1536,  sAw + 24*64);
        glds16(Bh,           sBw);
        glds16(Bh + 8*512,   sBw + 8*64);
        glds16(Bh + 16*512,  sBw + 16*64);
        glds16(Bh + 24*512,  sBw + 24*64);
        __syncthreads();
        #pragma unroll
        for(int ks=0; ks<2; ks++){
            int kc = ks*4 + quad;
            s16x8 af[4], bfr[4];
            #pragma unroll
            for(int i=0;i<4;i++){
                int r = wm*64 + i*16 + l15;
                af[i] = *(const s16x8*)&sA[r*64 + ((kc ^ (r&7))<<3)];
            }
            #pragma unroll
            for(int j=0;j<4;j++){
                int r = wn*64 + j*16 + l15;
                bfr[j] = *(const s16x8*)&sB[r*64 + ((kc ^ (r&7))<<3)];
            }
            #pragma unroll
            for(int i=0;i<4;i++)
                #pragma unroll
                for(int j=0;j<4;j++)
                    acc[i][j] = __builtin_amdgcn_mfma_f32_16x16x32_bf16(bfr[j], af[i], acc[i][j], 0,0,0);
        }
        __syncthreads();
    }

    // swapped layout: lane holds row = row0+i*16+l15, cols = col0+j*16+quad*4..+3
    int row0 = b*4096 + mr*128 + wm*64;
    int col0 = nt*128 + wn*64;
    float4 bv[4];
    #pragma unroll
    for(int j=0;j<4;j++) bv[j] = *(const float4*)&bias[col0 + j*16 + quad*4];
    #pragma unroll
    for(int i=0;i<4;i++){
        size_t rb = (size_t)(row0 + i*16 + l15)*512 + col0;
        #pragma unroll
        for(int j=0;j<4;j++){
            float4 o;
            o.x = acc[i][j][0] + bv[j].x;
            o.y = acc[i][j][1] + bv[j].y;
            o.z = acc[i][j][2] + bv[j].z;
            o.w = acc[i][j][3] + bv[j].w;
            *(float4*)&out[rb + j*16 + quad*4] = o;
        }
    }
}

extern "C" void kernel_launch(void* const* d_in, const int* in_sizes, int n_in,
                              void* d_out, int out_size, void* d_ws, size_t ws_size,
                              hipStream_t stream){
    const float* x      = (const float*)d_in[0];
    const float* wqkv_w = (const float*)d_in[1];
    const float* wqkv_b = (const float*)d_in[2];
    const float* wp_w   = (const float*)d_in[3];
    const float* wp_b   = (const float*)d_in[4];

    char* ws = (char*)d_ws;
    us*    qkvbf  = (us*)(ws);                    // 96 MB
    us*    xbf    = (us*)(ws + 100663296);        // 32 MB
    float* Spart  = (float*)(ws + 134217728);     // 8 MB
    us*    Mcat   = (us*)(ws + 143130624);        // 4 MB
    us*    wqkvbf = (us*)(ws + 147324928);        // 1.5 MB
    us*    wpbf   = (us*)(ws + 148897792);        // 0.5 MB

    cast_all<<<17408,256,0,stream>>>(x, wqkv_w, wp_w, xbf, wqkvbf, wpbf);

    gemm_qkv<<<3072,256,0,stream>>>(xbf, wqkvbf, wqkv_b, qkvbf);

    attn_scores_mfma<<<dim3(8,64),256,0,stream>>>(qkvbf, Spart);
    softfold<<<256,256,0,stream>>>(Spart, wpbf, Mcat);

    gemm_vout<<<1024,256,0,stream>>>(qkvbf, Mcat, wp_b, (float*)d_out);
}